// Round 2
// baseline (224.103 us; speedup 1.0000x reference)
//
#include <hip/hip_runtime.h>

#define N_NODES 100000
#define N_EDGES 1600000
#define D 64
#define NBUCKET 391              // ceil(N_NODES/256), bucket = 256 dst nodes
#define QCAP_B 4800              // per-bucket queue cap (mean 4096, sd ~64)
#define EPB 4096                 // edges per sort block
#define SORT_BLOCKS 391          // ceil(N_EDGES/EPB)

typedef unsigned short u16;
typedef short bf16x8 __attribute__((ext_vector_type(8)));
typedef short s16x4  __attribute__((ext_vector_type(4)));
typedef float f32x4  __attribute__((ext_vector_type(4)));

__device__ __forceinline__ float bf2f(u16 u) {
    unsigned v = (unsigned)u << 16;
    float f;
    __builtin_memcpy(&f, &v, 4);
    return f;
}
__device__ __forceinline__ u16 f2bf(float f) {
    unsigned u;
    __builtin_memcpy(&u, &f, 4);
    u = (u + 0x7FFFu + ((u >> 16) & 1u)) >> 16;
    return (u16)u;
}

// ---------------------------------------------------------------------------
// x (f32) -> xb (bf16), 4 elems/thread.
// ---------------------------------------------------------------------------
__global__ __launch_bounds__(256) void convert_kernel(
    const float* __restrict__ x, u16* __restrict__ xb)
{
    int i = blockIdx.x * 256 + threadIdx.x;
    float4 v = ((const float4*)x)[i];
    ushort4 o;
    o.x = f2bf(v.x); o.y = f2bf(v.y); o.z = f2bf(v.z); o.w = f2bf(v.w);
    ((ushort4*)xb)[i] = o;
}

// ---------------------------------------------------------------------------
// Pack W1/W2 (fp32 64x64) into bf16 MFMA B-fragment order.
// frag f = (layer*4 + ct)*2 + kf holds B[k=kf*32+quad*8+j][n=ct*16+(lane&15)]
// at u16 offset f*512 + lane*8 + j.
// ---------------------------------------------------------------------------
__global__ __launch_bounds__(256) void prep_weights_kernel(
    const float* __restrict__ W1, const float* __restrict__ W2,
    u16* __restrict__ Wf)
{
    int t = blockIdx.x * 256 + threadIdx.x;   // 16 frags * 64 lanes = 1024
    if (t >= 16 * 64) return;
    int f = t >> 6, lane = t & 63;
    int layer = f >> 3, ct = (f >> 1) & 3, kf = f & 1;
    const float* W = layer ? W2 : W1;
    int col = ct * 16 + (lane & 15);
    int krow = kf * 32 + (lane >> 4) * 8;
    u16* o = Wf + f * 512 + lane * 8;
#pragma unroll
    for (int j = 0; j < 8; ++j)
        o[j] = f2bf(W[(krow + j) * D + col]);
}

// ---------------------------------------------------------------------------
// Block-level counting sort of 4096 edges into 391 bucket queues (r9/r10).
// Entry packs (dst&255)<<17 | src.
// ---------------------------------------------------------------------------
__global__ __launch_bounds__(256) void sort_kernel(
    const int* __restrict__ ei, int* __restrict__ qtail,
    unsigned* __restrict__ queue)
{
    __shared__ int cnt[512];
    __shared__ int scan[512];
    __shared__ int gbase[512];
    __shared__ int run[512];
    __shared__ unsigned staged[EPB];
    __shared__ int gposa[EPB];

    int tid = threadIdx.x;
    int e0 = blockIdx.x * EPB;

    cnt[tid] = 0; cnt[tid + 256] = 0;
    run[tid] = 0; run[tid + 256] = 0;
    __syncthreads();

    for (int i = tid; i < EPB; i += 256) {
        int e = e0 + i;
        if (e < N_EDGES) {
            int dst = ei[N_EDGES + e];
            atomicAdd(&cnt[dst >> 8], 1);
        }
    }
    __syncthreads();
    scan[tid] = cnt[tid]; scan[tid + 256] = cnt[tid + 256];
    __syncthreads();
    for (int off = 1; off < 512; off <<= 1) {
        int v1 = (tid >= off) ? scan[tid - off] : 0;
        int v2 = scan[tid + 256 - off];
        __syncthreads();
        scan[tid] += v1;
        scan[tid + 256] += v2;
        __syncthreads();
    }
    if (tid < NBUCKET && cnt[tid] > 0)
        gbase[tid] = atomicAdd(&qtail[tid], cnt[tid]);
    int b2 = tid + 256;
    if (b2 < NBUCKET && cnt[b2] > 0)
        gbase[b2] = atomicAdd(&qtail[b2], cnt[b2]);
    __syncthreads();

    for (int i = tid; i < EPB; i += 256) {
        int e = e0 + i;
        if (e < N_EDGES) {
            int dst = ei[N_EDGES + e];
            int src = ei[e];
            int b = dst >> 8;
            int r = atomicAdd(&run[b], 1);
            int slot = scan[b] - cnt[b] + r;
            staged[slot] = ((unsigned)(dst & 255) << 17) | (unsigned)src;
            int gp = gbase[b] + r;
            gposa[slot] = (gp < QCAP_B) ? b * QCAP_B + gp : -1;
        }
    }
    __syncthreads();

    int total = scan[511];
    for (int i = tid; i < total; i += 256) {
        int gp = gposa[i];
        if (gp >= 0) queue[gp] = staged[i];
    }
}

// ---------------------------------------------------------------------------
// Per-bucket LDS counting sort -> exact CSR. Zero global atomics (r10).
// ---------------------------------------------------------------------------
__global__ __launch_bounds__(256) void bin3_kernel(
    const unsigned* __restrict__ queue, const int* __restrict__ qtail,
    int* __restrict__ cnt_out, int* __restrict__ row_start,
    int* __restrict__ sorted_src)
{
    __shared__ int cnt[256];
    __shared__ int scanv[256];
    __shared__ int run[256];
    __shared__ unsigned staged[QCAP_B];

    int tid = threadIdx.x;
    int b = blockIdx.x;
    cnt[tid] = 0; run[tid] = 0;
    __syncthreads();

    int n = min(qtail[b], QCAP_B);
    const unsigned* q = queue + (size_t)b * QCAP_B;

    for (int i = tid; i < n; i += 256) {
        unsigned e = q[i];
        staged[i] = e;
        atomicAdd(&cnt[e >> 17], 1);
    }
    __syncthreads();
    scanv[tid] = cnt[tid];
    __syncthreads();
    for (int off = 1; off < 256; off <<= 1) {
        int v = (tid >= off) ? scanv[tid - off] : 0;
        __syncthreads();
        scanv[tid] += v;
        __syncthreads();
    }

    int gb = b * QCAP_B;
    int node = b * 256 + tid;
    if (node < N_NODES) {
        cnt_out[node] = cnt[tid];
        row_start[node] = gb + scanv[tid] - cnt[tid];
    }

    for (int i = tid; i < n; i += 256) {
        unsigned e = staged[i];
        int r = (int)(e >> 17);
        int k = atomicAdd(&run[r], 1);
        int pos = gb + (scanv[r] - cnt[r]) + k;
        sorted_src[pos] = (int)(e & 0x1FFFFu);
    }
}

// ---------------------------------------------------------------------------
// FUSED gather + 2-layer MFMA MLP. Block = 256 = 4 waves; wave = 16 nodes.
// Gather phase: 4 lanes/node (lane&15 = node, quad = which lanes of the 4);
// each lane owns the node-row chunks [quad*8..+7] and [32+quad*8..+7] — which
// is EXACTLY the MFMA A-fragment layout, so aggregation accumulates straight
// into A-frag registers (no xa round trip). One dwordx4 wave-load gathers 8
// rows (1KB). Edge indices broadcast within the node's 4 lanes (stride-16)
// via ds_bpermute; per-group tails pad to the zeroed dummy row N_NODES.
// MLP phase: identical to the previous gin_mlp_kernel (wave-private LDS
// round trip for the hidden layer, no __syncthreads).
// ---------------------------------------------------------------------------
#define US 68   // u16 stride per node row in LDS (136 B)

template <int WRITE_BF16>
__global__ __launch_bounds__(256) void gin_fused_kernel(
    const u16* __restrict__ xb, const int* __restrict__ cnt_arr,
    const int* __restrict__ row_start, const int* __restrict__ sorted_src,
    const u16* __restrict__ Wf, const float* __restrict__ b1,
    const float* __restrict__ b2, float* __restrict__ outf,
    u16* __restrict__ outb)
{
    __shared__ u16 us[64 * US];   // 8704 B

    int tid  = threadIdx.x;
    int lane = tid & 63;
    int w    = tid >> 6;
    int quad = lane >> 4;
    int l16  = lane & 15;
    int n0   = blockIdx.x * 64 + w * 16;
    int node = n0 + l16;
    bool valid = node < N_NODES;

    int cnt  = valid ? cnt_arr[node] : 0;
    int base = valid ? row_start[node] : 0;

    // ---- gather: acc = x[node] + sum_{j->node} x[j], straight into A-frag
    // layout. accl*/acch* [i] hold cols {2i, 2i+1} of the lane's two chunks.
    size_t rb = (size_t)(valid ? node : N_NODES) * D + quad * 8;
    uint4 sv0 = *(const uint4*)(xb + rb);
    uint4 sv1 = *(const uint4*)(xb + rb + 32);
    float l0[4], h0[4], l1[4], h1[4];
#pragma unroll
    for (int i = 0; i < 4; ++i) {
        unsigned d0 = ((const unsigned*)&sv0)[i];
        unsigned d1 = ((const unsigned*)&sv1)[i];
        unsigned t0 = d0 << 16, t1 = d0 & 0xFFFF0000u;
        unsigned t2 = d1 << 16, t3 = d1 & 0xFFFF0000u;
        __builtin_memcpy(&l0[i], &t0, 4);
        __builtin_memcpy(&h0[i], &t1, 4);
        __builtin_memcpy(&l1[i], &t2, 4);
        __builtin_memcpy(&h1[i], &t3, 4);
    }

    // wave-group (16-node) max degree -> common trip count
    int mc = cnt;
    mc = max(mc, __shfl_xor(mc, 1));
    mc = max(mc, __shfl_xor(mc, 2));
    mc = max(mc, __shfl_xor(mc, 4));
    mc = max(mc, __shfl_xor(mc, 8));

    for (int c = 0; c < mc; c += 4) {
        // lane (l16, quad) prefetches edge c+quad of node l16;
        // past-degree slots point at the zeroed dummy row N_NODES.
        int s = (c + quad < cnt) ? sorted_src[base + c + quad] : N_NODES;
#pragma unroll
        for (int j = 0; j < 4; ++j) {
            int idx = __builtin_amdgcn_ds_bpermute((l16 + j * 16) << 2, s);
            const u16* rp = xb + ((size_t)(unsigned)idx << 6) + quad * 8;
            uint4 v0 = *(const uint4*)rp;
            uint4 v1 = *(const uint4*)(rp + 32);
#pragma unroll
            for (int i = 0; i < 4; ++i) {
                unsigned d0 = ((const unsigned*)&v0)[i];
                unsigned d1 = ((const unsigned*)&v1)[i];
                unsigned t0 = d0 << 16, t1 = d0 & 0xFFFF0000u;
                unsigned t2 = d1 << 16, t3 = d1 & 0xFFFF0000u;
                float f0, f1, f2, f3;
                __builtin_memcpy(&f0, &t0, 4);
                __builtin_memcpy(&f1, &t1, 4);
                __builtin_memcpy(&f2, &t2, 4);
                __builtin_memcpy(&f3, &t3, 4);
                l0[i] += f0; h0[i] += f1;
                l1[i] += f2; h1[i] += f3;
            }
        }
    }

    // pack accumulators -> bf16 A-frags (dword i = cols {2i, 2i+1})
    unsigned pk[4];
#pragma unroll
    for (int i = 0; i < 4; ++i)
        pk[i] = (unsigned)f2bf(l0[i]) | ((unsigned)f2bf(h0[i]) << 16);
    bf16x8 a0; __builtin_memcpy(&a0, pk, 16);
#pragma unroll
    for (int i = 0; i < 4; ++i)
        pk[i] = (unsigned)f2bf(l1[i]) | ((unsigned)f2bf(h1[i]) << 16);
    bf16x8 a1; __builtin_memcpy(&a1, pk, 16);

    // ---- layer 1: u = relu(a @ W1 + b1) ----
    f32x4 acc[4];
#pragma unroll
    for (int ct = 0; ct < 4; ++ct) {
        float bv = b1[ct * 16 + l16];
        acc[ct] = (f32x4){bv, bv, bv, bv};
        bf16x8 bf0 = *(const bf16x8*)(Wf + (size_t)((0 * 4 + ct) * 2 + 0) * 512 + lane * 8);
        bf16x8 bf1 = *(const bf16x8*)(Wf + (size_t)((0 * 4 + ct) * 2 + 1) * 512 + lane * 8);
        acc[ct] = __builtin_amdgcn_mfma_f32_16x16x32_bf16(a0, bf0, acc[ct], 0, 0, 0);
        acc[ct] = __builtin_amdgcn_mfma_f32_16x16x32_bf16(a1, bf1, acc[ct], 0, 0, 0);
    }

    // relu -> bf16 -> wave-private LDS rows (C-layout: row=quad*4+r, col)
#pragma unroll
    for (int ct = 0; ct < 4; ++ct)
#pragma unroll
        for (int r = 0; r < 4; ++r)
            us[(w * 16 + quad * 4 + r) * US + ct * 16 + l16] =
                f2bf(fmaxf(acc[ct][r], 0.f));

    // ---- layer 2: v = u @ W2 + b2 ----
    const u16* ub = &us[(w * 16 + l16) * US + quad * 8];
    s16x4 lo0 = *(const s16x4*)ub;
    s16x4 hi0 = *(const s16x4*)(ub + 4);
    s16x4 lo1 = *(const s16x4*)(ub + 32);
    s16x4 hi1 = *(const s16x4*)(ub + 36);
    bf16x8 u0 = __builtin_shufflevector(lo0, hi0, 0, 1, 2, 3, 4, 5, 6, 7);
    bf16x8 u1 = __builtin_shufflevector(lo1, hi1, 0, 1, 2, 3, 4, 5, 6, 7);

#pragma unroll
    for (int ct = 0; ct < 4; ++ct) {
        float bv = b2[ct * 16 + l16];
        acc[ct] = (f32x4){bv, bv, bv, bv};
        bf16x8 bf0 = *(const bf16x8*)(Wf + (size_t)((1 * 4 + ct) * 2 + 0) * 512 + lane * 8);
        bf16x8 bf1 = *(const bf16x8*)(Wf + (size_t)((1 * 4 + ct) * 2 + 1) * 512 + lane * 8);
        acc[ct] = __builtin_amdgcn_mfma_f32_16x16x32_bf16(u0, bf0, acc[ct], 0, 0, 0);
        acc[ct] = __builtin_amdgcn_mfma_f32_16x16x32_bf16(u1, bf1, acc[ct], 0, 0, 0);
    }

    // epilogue (C-layout scatter; 16-lane groups write contiguous runs)
#pragma unroll
    for (int r = 0; r < 4; ++r) {
        int nd = n0 + quad * 4 + r;
        if (nd >= N_NODES) continue;
#pragma unroll
        for (int ct = 0; ct < 4; ++ct) {
            if (WRITE_BF16)
                outb[(size_t)nd * D + ct * 16 + l16] = f2bf(fmaxf(acc[ct][r], 0.f));
            else
                outf[(size_t)nd * D + ct * 16 + l16] = acc[ct][r];
        }
    }
}

extern "C" void kernel_launch(void* const* d_in, const int* in_sizes, int n_in,
                              void* d_out, int out_size, void* d_ws, size_t ws_size,
                              hipStream_t stream)
{
    const float* x  = (const float*)d_in[0];
    const int*   ei = (const int*)d_in[1];
    const float* W1 = (const float*)d_in[2];
    const float* b1 = (const float*)d_in[3];
    const float* W2 = (const float*)d_in[4];
    const float* b2 = (const float*)d_in[5];
    float* out = (float*)d_out;

    // workspace (~41.5 MB):
    //   qtail(512) | cnt(100096) | row_start(100096)
    //   queue (391*4800 u32) | sorted_src (391*4800 int)
    //   Wf (8192 u16) | xa_b ((N+1) rows bf16, = hb) | xb_b ((N+1) rows bf16)
    int* qtail      = (int*)d_ws;
    int* cnt_arr    = qtail + 512;
    int* row_start  = cnt_arr + 100096;
    unsigned* queue = (unsigned*)(row_start + 100096);
    int* sorted_src = (int*)(queue + (size_t)NBUCKET * QCAP_B);
    u16* Wf         = (u16*)(sorted_src + (size_t)NBUCKET * QCAP_B);
    u16* xa_b       = Wf + 8192;
    u16* xb_b       = xa_b + (size_t)(N_NODES + 1) * D;

    const int mlp_blocks = (N_NODES + 63) / 64;     // 1563

    // ---- prep: qtail zero, dummy zero rows, x -> bf16, weights, sort, CSR --
    hipMemsetAsync(qtail, 0, 512 * sizeof(int), stream);
    hipMemsetAsync(xa_b + (size_t)N_NODES * D, 0, D * sizeof(u16), stream);
    hipMemsetAsync(xb_b + (size_t)N_NODES * D, 0, D * sizeof(u16), stream);
    convert_kernel<<<(N_NODES * D / 4) / 256, 256, 0, stream>>>(x, xb_b);
    prep_weights_kernel<<<4, 256, 0, stream>>>(W1, W2, Wf);
    sort_kernel<<<SORT_BLOCKS, 256, 0, stream>>>(ei, qtail, queue);
    bin3_kernel<<<NBUCKET, 256, 0, stream>>>(queue, qtail, cnt_arr, row_start, sorted_src);

    // ---- layer 1: hb(xa_b) = relu(MLP(xb + gather(xb))) ----
    gin_fused_kernel<1><<<mlp_blocks, 256, 0, stream>>>(
        xb_b, cnt_arr, row_start, sorted_src, Wf, b1, b2, nullptr, xa_b);

    // ---- layer 2: out = MLP(hb + gather(hb)) ----
    gin_fused_kernel<0><<<mlp_blocks, 256, 0, stream>>>(
        xa_b, cnt_arr, row_start, sorted_src, Wf, b1, b2, out, nullptr);
}